// Round 2
// baseline (84.531 us; speedup 1.0000x reference)
//
#include <hip/hip_runtime.h>

#define N 1024
#define H 64
#define E (N * (N - 1))   // 1047552

// Kernel 1: per-node halves of the first Linear.
//   A[i][h] = b1[h] + sum_k emb[i][k] * W1[k][h]       (top half of W1)
//   B[i][h] =         sum_k emb[i][k] * W1[H+k][h]     (bottom half of W1)
// Block = 256 threads = 4 k-slices x 64 h lanes; LDS reduce over slices.
// 1024 blocks -> 4096 waves -> 16 waves/CU (was 4/CU: latency-bound).
__global__ __launch_bounds__(256) void precompute_ab(
    const float* __restrict__ emb, const float* __restrict__ W1,
    const float* __restrict__ b1, float* __restrict__ A, float* __restrict__ Bm)
{
    __shared__ float pa[4][64];
    __shared__ float pb[4][64];
    const int i  = blockIdx.x;
    const int h  = threadIdx.x & 63;
    const int ks = threadIdx.x >> 6;          // k-slice: 16 k's each

    const float* er  = emb + i * H + ks * 16;        // uniform within wave
    const float* w1a = W1 + (ks * 16) * H + h;       // coalesced across h
    const float* w1b = W1 + (H + ks * 16) * H + h;

    float a = 0.f, b = 0.f;
#pragma unroll
    for (int k = 0; k < 16; ++k) {
        const float ev = er[k];               // wave-uniform -> scalar load
        a = fmaf(ev, w1a[k * H], a);
        b = fmaf(ev, w1b[k * H], b);
    }
    pa[ks][h] = a;
    pb[ks][h] = b;
    __syncthreads();
    if (threadIdx.x < 64) {
        const float va = b1[h] + (pa[0][h] + pa[1][h]) + (pa[2][h] + pa[3][h]);
        const float vb = (pb[0][h] + pb[1][h]) + (pb[2][h] + pb[3][h]);
        A[i * H + h]  = va;
        Bm[i * H + h] = vb;
    }
}

#define ITILE 8

// Kernel 2: each thread owns one j (B[j] in 64 VGPRs), loops ITILE uniform
// i values (A-row + w2 are wave-uniform L1-broadcast loads). Writes are
// coalesced: for fixed i, consecutive j -> consecutive e.
// ii loop is NOT unrolled: keeps only one i's 16 float4 A-loads live
// (fully unrolled version had ~128 live loads -> VGPR spill to scratch).
__global__ __launch_bounds__(256) void edge_kernel(
    const float* __restrict__ A, const float* __restrict__ Bm,
    const float* __restrict__ W2, const float* __restrict__ b2,
    float* __restrict__ out)
{
    const int j  = blockIdx.x * 256 + threadIdx.x;  // gridDim.x = N/256
    const int i0 = blockIdx.y * ITILE;              // gridDim.y = N/ITILE

    float4 breg[16];                                 // 64 VGPRs
    const float4* bp = (const float4*)(Bm + j * H);
#pragma unroll
    for (int q = 0; q < 16; ++q) breg[q] = bp[q];

    float4 wreg[16];                                 // uniform; 64 regs
    const float4* wp = (const float4*)W2;
#pragma unroll
    for (int q = 0; q < 16; ++q) wreg[q] = wp[q];
    const float bias2 = b2[0];

#pragma unroll 1
    for (int ii = 0; ii < ITILE; ++ii) {
        const int i = i0 + ii;
        const float4* ap = (const float4*)(A + i * H);  // wave-uniform addr
        float a0 = 0.f, a1 = 0.f, a2 = 0.f, a3 = 0.f;   // break FMA dep chain
#pragma unroll
        for (int q = 0; q < 16; ++q) {
            const float4 a = ap[q];
            const float4 b = breg[q];
            const float4 w = wreg[q];
            a0 = fmaf(fmaxf(a.x + b.x, 0.f), w.x, a0);
            a1 = fmaf(fmaxf(a.y + b.y, 0.f), w.y, a1);
            a2 = fmaf(fmaxf(a.z + b.z, 0.f), w.z, a2);
            a3 = fmaf(fmaxf(a.w + b.w, 0.f), w.w, a3);
        }
        const float x = (a0 + a1) + (a2 + a3) + bias2;
        const float s = __builtin_amdgcn_rcpf(1.f + __expf(-x));  // v_rcp_f32
        if (j != i) {
            const int e = i * (N - 1) + (j < i ? j : j - 1);
            out[e]         = (float)i;   // edge_index row 0
            out[E + e]     = (float)j;   // edge_index row 1
            out[2 * E + e] = s;          // edge_weights
        }
    }
}

extern "C" void kernel_launch(void* const* d_in, const int* in_sizes, int n_in,
                              void* d_out, int out_size, void* d_ws, size_t ws_size,
                              hipStream_t stream) {
    const float* emb = (const float*)d_in[0];   // [N, H]
    const float* W1  = (const float*)d_in[1];   // [2H, H]
    const float* b1  = (const float*)d_in[2];   // [H]
    const float* W2  = (const float*)d_in[3];   // [H, 1]
    const float* b2  = (const float*)d_in[4];   // [1]

    float* A  = (float*)d_ws;                   // [N, H]
    float* Bm = A + N * H;                      // [N, H]  (512 KB of ws)

    precompute_ab<<<N, 256, 0, stream>>>(emb, W1, b1, A, Bm);

    dim3 grid(N / 256, N / ITILE);              // (4, 128) = 512 blocks
    edge_kernel<<<grid, 256, 0, stream>>>(A, Bm, W2, b2, (float*)d_out);
}